// Round 9
// baseline (2207.387 us; speedup 1.0000x reference)
//
#include <hip/hip_runtime.h>
#include <cstdint>

// ---------------- fast device math (raw v_exp_f32 / v_rcp_f32) ----------------
__device__ __forceinline__ float fexp2(float x) { return __builtin_amdgcn_exp2f(x); }
__device__ __forceinline__ float frcp(float x)  { return __builtin_amdgcn_rcpf(x); }

__device__ __forceinline__ float fast_tanh(float x) {
    x = fminf(15.0f, fmaxf(-15.0f, x));
    float E = fexp2(x * 2.8853900817779268f);   // exp(2x) = 2^(2x*log2e)
    float d = E + 1.0f;
    float r = frcp(d);
    r = r * (2.0f - d * r);                      // Newton -> ~fp32 precise
    return (E - 1.0f) * r;
}

// ---------------- tiled fp32 GEMM v2: 128x64 tile, 8x4 micro, dbuf 1-barrier --
#define GBM 128
#define GBN 64
#define GBK 16

template<bool TANH>
__global__ __launch_bounds__(256) void gemm_bias2(
    const float* __restrict__ A, const float* __restrict__ W,
    const float* __restrict__ bias, float* __restrict__ C,
    int M, int N, int K)
{
    __shared__ float As[2][GBK][GBM + 4];   // 2 x 16 x 132 x 4B = 16.9 KB
    __shared__ float Bs[2][GBK][GBN + 4];   // 2 x 16 x 68  x 4B =  8.7 KB

    const int tid = threadIdx.x;
    const int tx = tid & 15;          // n-quad (4 cols)
    const int ty = tid >> 4;          // m-oct  (8 rows)
    const int m0 = blockIdx.y * GBM;
    const int n0 = blockIdx.x * GBN;

    float acc[8][4] = {};
    float ra[8], rb[4];

    const int T = (K + GBK - 1) / GBK;

    // prologue: tile 0 -> LDS buf 0
    #pragma unroll
    for (int ld = 0; ld < 8; ++ld) {
        int e = tid + ld * 256, kk = e & 15, mm = e >> 4;
        As[0][kk][mm] = (kk < K) ? A[(size_t)(m0 + mm) * K + kk] : 0.0f;
    }
    #pragma unroll
    for (int ld = 0; ld < 4; ++ld) {
        int e = tid + ld * 256, nn = e & 63, kk = e >> 6;
        int ng = n0 + nn;
        Bs[0][kk][nn] = (kk < K && ng < N) ? W[(size_t)kk * N + ng] : 0.0f;
    }
    __syncthreads();

    for (int t = 0; t < T; ++t) {
        const int cb = t & 1;
        const bool more = (t + 1 < T);
        // issue next tile's global loads early (latency hides under compute)
        if (more) {
            int k0 = (t + 1) * GBK;
            #pragma unroll
            for (int ld = 0; ld < 8; ++ld) {
                int e = tid + ld * 256, kk = e & 15, mm = e >> 4;
                int kg = k0 + kk;
                ra[ld] = (kg < K) ? A[(size_t)(m0 + mm) * K + kg] : 0.0f;
            }
            #pragma unroll
            for (int ld = 0; ld < 4; ++ld) {
                int e = tid + ld * 256, nn = e & 63, kk = e >> 6;
                int kg = k0 + kk, ng = n0 + nn;
                rb[ld] = (kg < K && ng < N) ? W[(size_t)kg * N + ng] : 0.0f;
            }
        }
        // compute on current buffer
        #pragma unroll
        for (int kk = 0; kk < GBK; ++kk) {
            float4 a0 = *(const float4*)&As[cb][kk][ty * 8];
            float4 a1 = *(const float4*)&As[cb][kk][ty * 8 + 4];
            float4 b0 = *(const float4*)&Bs[cb][kk][tx * 4];
            float av[8] = {a0.x, a0.y, a0.z, a0.w, a1.x, a1.y, a1.z, a1.w};
            float bv[4] = {b0.x, b0.y, b0.z, b0.w};
            #pragma unroll
            for (int i2 = 0; i2 < 8; ++i2)
                #pragma unroll
                for (int j2 = 0; j2 < 4; ++j2)
                    acc[i2][j2] = fmaf(av[i2], bv[j2], acc[i2][j2]);
        }
        // stage regs -> other buffer; ONE barrier per K-tile
        if (more) {
            #pragma unroll
            for (int ld = 0; ld < 8; ++ld) {
                int e = tid + ld * 256, kk = e & 15, mm = e >> 4;
                As[cb ^ 1][kk][mm] = ra[ld];
            }
            #pragma unroll
            for (int ld = 0; ld < 4; ++ld) {
                int e = tid + ld * 256, nn = e & 63, kk = e >> 6;
                Bs[cb ^ 1][kk][nn] = rb[ld];
            }
            __syncthreads();
        }
    }

    // epilogue
    const int cbase = n0 + tx * 4;
    if (cbase >= N) return;
    float bb[4];
    if (cbase + 3 < N) {
        float4 b4 = *(const float4*)&bias[cbase];
        bb[0] = b4.x; bb[1] = b4.y; bb[2] = b4.z; bb[3] = b4.w;
    } else {
        #pragma unroll
        for (int e = 0; e < 4; ++e) bb[e] = (cbase + e < N) ? bias[cbase + e] : 0.0f;
    }
    #pragma unroll
    for (int i2 = 0; i2 < 8; ++i2) {
        int row = m0 + ty * 8 + i2;
        float o[4];
        #pragma unroll
        for (int j2 = 0; j2 < 4; ++j2) {
            float v = acc[i2][j2] + bb[j2];
            o[j2] = TANH ? fast_tanh(v) : v;
        }
        if (cbase + 3 < N) {
            float4 o4 = {o[0], o[1], o[2], o[3]};
            *(float4*)&C[(size_t)row * N + cbase] = o4;
        } else {
            #pragma unroll
            for (int j2 = 0; j2 < 4; ++j2)
                if (cbase + j2 < N) C[(size_t)row * N + cbase + j2] = o[j2];
        }
    }
}

// ---------------- decoder layer 1 (K=4) --------------------------------------
__global__ __launch_bounds__(256) void dec_l1(
    const float* __restrict__ Mo, const float* __restrict__ Wd,
    const float* __restrict__ bd, float* __restrict__ O)
{
    int idx = blockIdx.x * 256 + threadIdx.x;
    int r  = idx / 125;
    int c4 = (idx % 125) * 4;
    float4 m = *(const float4*)&Mo[(size_t)r * 4];
    float4 w0 = *(const float4*)&Wd[0 * 500 + c4];
    float4 w1 = *(const float4*)&Wd[1 * 500 + c4];
    float4 w2 = *(const float4*)&Wd[2 * 500 + c4];
    float4 w3 = *(const float4*)&Wd[3 * 500 + c4];
    float4 b  = *(const float4*)&bd[c4];
    float o0 = b.x + m.x * w0.x + m.y * w1.x + m.z * w2.x + m.w * w3.x;
    float o1 = b.y + m.x * w0.y + m.y * w1.y + m.z * w2.y + m.w * w3.y;
    float o2 = b.z + m.x * w0.z + m.y * w1.z + m.z * w2.z + m.w * w3.z;
    float o3 = b.w + m.x * w0.w + m.y * w1.w + m.z * w2.w + m.w * w3.w;
    float4 o = {fast_tanh(o0), fast_tanh(o1), fast_tanh(o2), fast_tanh(o3)};
    *(float4*)&O[(size_t)r * 500 + c4] = o;
}

// ---------------- LTC scan: split-j butterfly + pairwise rcp -----------------
// R8 structure (best: 1532us) + pairwise reciprocal in the unfold loop:
//   WE_a/F_a + WE_b/F_b = (WE_a*F_b + WE_b*F_a) * rcp(F_a*F_b)
// Chain depth identical to direct rcp (mul->rcp->fma vs add->rcp->fma);
// numerators compute in parallel with the rcp. Trans/wave-unfold 17 -> 13.
// Overflow-safe: |v|<=1 (convex comb of v,vleak,erev,serev) -> F<=2^21,
// pair product <= 2^42. Sensory path keeps per-syn rcp (|x| can reach ~50).
#define SEQ_T 512

__global__ __launch_bounds__(512, 2) void ltc_scan(
    const float* __restrict__ h,       // [32][512][20]
    const float* __restrict__ gleak, const float* __restrict__ vleak,
    const float* __restrict__ cm,
    const float* __restrict__ w,  const float* __restrict__ mu,
    const float* __restrict__ sg, const float* __restrict__ erev,
    const float* __restrict__ sw,  const float* __restrict__ smu,
    const float* __restrict__ ssg, const float* __restrict__ serev,
    const float* __restrict__ in_w, const float* __restrict__ in_b,
    const float* __restrict__ out_w, const float* __restrict__ out_b,
    float* __restrict__ motor)         // [32][512][4]
{
    const int b   = blockIdx.x;
    const int tid = threadIdx.x;
    const int w8  = tid >> 6;          // wave 0..7
    const int l   = tid & 63;
    const int jl  = l & 7;
    const int ig  = l >> 3;
    const int j   = 8 * w8 + jl;       // this lane's output unit

    const float LOG2E = 1.4426950408889634f;

    __shared__ float vbuf[2][64];

    // unfold params for (i = 8*ig + r, j)
    float A1[8], B1[8], Wp[8], WE[8];
    #pragma unroll
    for (int r = 0; r < 8; ++r) {
        int i = 8 * ig + r;
        float s = sg[i * 64 + j];
        A1[r] = s * LOG2E;
        B1[r] = mu[i * 64 + j] * s * LOG2E;
        Wp[r] = w[i * 64 + j];
        WE[r] = Wp[r] * erev[i * 64 + j];
    }
    // sensory: lane handles i in {ig, ig+8, ig+16 if ig<4} for its j
    float sA[3], sB[3], sWp[3], sWE[3], uw[3], ub[3];
    int   sI[3];
    #pragma unroll
    for (int r = 0; r < 3; ++r) {
        int i = ig + 8 * r;
        bool live = (i < 20);
        sI[r] = live ? i : 0;
        float s = ssg[sI[r] * 64 + j];
        sA[r]  = s * LOG2E;
        sB[r]  = smu[sI[r] * 64 + j] * s * LOG2E;
        sWp[r] = live ? sw[sI[r] * 64 + j] : 0.0f;
        sWE[r] = live ? sWp[r] * serev[sI[r] * 64 + j] : 0.0f;
        uw[r]  = in_w[sI[r]];
        ub[r]  = in_b[sI[r]];
    }

    const float cmt  = cm[j] * 6.0f;
    const float gl   = gleak[j];
    const float glvl = gl * vleak[j];
    const float gle  = cmt + gl + 1e-8f;
    const float ow   = out_w[j & 3], ob = out_b[j & 3];

    float vj = 0.0f;                   // this lane's own v_j
    const float* hb = h + (size_t)b * SEQ_T * 20;
    float* mb = motor + (size_t)b * SEQ_T * 4;

    float u_cur[3], u_nxt[3];
    #pragma unroll
    for (int r = 0; r < 3; ++r) u_cur[r] = hb[sI[r]];

    if (tid < 64) vbuf[0][tid] = 0.0f;
    __syncthreads();

    int cur = 0;
    for (int t = 0; t < SEQ_T; ++t) {
        int tn = (t + 1 < SEQ_T) ? (t + 1) : t;
        #pragma unroll
        for (int r = 0; r < 3; ++r) u_nxt[r] = hb[tn * 20 + sI[r]];

        // sensory per-lane partial, butterfly-reduced once per t
        float ns = 0.0f, ds = 0.0f;
        #pragma unroll
        for (int r = 0; r < 3; ++r) {
            float ui = fmaf(u_cur[r], uw[r], ub[r]);
            float x  = sB[r] - ui * sA[r];
            float E  = fexp2(x);
            float s  = frcp(1.0f + E);
            ns = fmaf(sWE[r], s, ns);
            ds = fmaf(sWp[r], s, ds);
        }
        ns += __shfl_xor(ns, 8);  ds += __shfl_xor(ds, 8);
        ns += __shfl_xor(ns, 16); ds += __shfl_xor(ds, 16);
        ns += __shfl_xor(ns, 32); ds += __shfl_xor(ds, 32);

        #pragma unroll 1
        for (int uf = 0; uf < 6; ++uf) {
            float4 va = *(const float4*)&vbuf[cur][8 * ig];
            float4 vc = *(const float4*)&vbuf[cur][8 * ig + 4];
            float vv[8] = {va.x, va.y, va.z, va.w, vc.x, vc.y, vc.z, vc.w};

            float F[8];
            #pragma unroll
            for (int r = 0; r < 8; ++r) {
                float x = fmaf(-vv[r], A1[r], B1[r]);
                F[r] = 1.0f + fexp2(x);
            }
            float an = 0.0f, ad = 0.0f;
            #pragma unroll
            for (int p = 0; p < 4; ++p) {
                float Fa = F[2*p], Fb = F[2*p+1];
                float rp = frcp(Fa * Fb);
                float na = fmaf(WE[2*p+1], Fa, WE[2*p] * Fb);
                float nd = fmaf(Wp[2*p+1], Fa, Wp[2*p] * Fb);
                an = fmaf(na, rp, an);
                ad = fmaf(nd, rp, ad);
            }
            // butterfly over ig bits (8,16,32): intra-wave, no LDS
            an += __shfl_xor(an, 8);  ad += __shfl_xor(ad, 8);
            an += __shfl_xor(an, 16); ad += __shfl_xor(ad, 16);
            an += __shfl_xor(an, 32); ad += __shfl_xor(ad, 32);

            float num = fmaf(cmt, vj, glvl) + an + ns;
            float den = gle + ad + ds;
            vj = num * frcp(den);

            if (ig == 0) vbuf[cur ^ 1][j] = vj;
            __syncthreads();
            cur ^= 1;
        }

        if (w8 == 0 && ig == 0 && jl < 4) mb[t * 4 + jl] = fmaf(vj, ow, ob);

        #pragma unroll
        for (int r = 0; r < 3; ++r) u_cur[r] = u_nxt[r];
    }
}

// ---------------- launch --------------------------------------------------
extern "C" void kernel_launch(void* const* d_in, const int* in_sizes, int n_in,
                              void* d_out, int out_size, void* d_ws, size_t ws_size,
                              hipStream_t stream) {
    const float* x      = (const float*)d_in[0];
    const float* enc_w0 = (const float*)d_in[1];
    const float* enc_b0 = (const float*)d_in[2];
    const float* enc_w1 = (const float*)d_in[3];
    const float* enc_b1 = (const float*)d_in[4];
    const float* enc_w2 = (const float*)d_in[5];
    const float* enc_b2 = (const float*)d_in[6];
    const float* dec_w0 = (const float*)d_in[7];
    const float* dec_b0 = (const float*)d_in[8];
    const float* dec_w1 = (const float*)d_in[9];
    const float* dec_b1 = (const float*)d_in[10];
    const float* dec_w2 = (const float*)d_in[11];
    const float* dec_b2 = (const float*)d_in[12];
    const float* gleak  = (const float*)d_in[13];
    const float* vleak  = (const float*)d_in[14];
    const float* cm     = (const float*)d_in[15];
    const float* w      = (const float*)d_in[16];
    const float* mu     = (const float*)d_in[17];
    const float* sigma  = (const float*)d_in[18];
    const float* erev   = (const float*)d_in[19];
    const float* sw     = (const float*)d_in[20];
    const float* smu    = (const float*)d_in[21];
    const float* ssigma = (const float*)d_in[22];
    const float* serev  = (const float*)d_in[23];
    const float* in_w   = (const float*)d_in[24];
    const float* in_b   = (const float*)d_in[25];
    const float* out_w  = (const float*)d_in[26];
    const float* out_b  = (const float*)d_in[27];

    float* ws   = (float*)d_ws;
    float* buf1 = ws;                       // 16384*500
    float* buf2 = ws + 8192000;             // 16384*500
    float* hbuf = ws + 16384000;            // 16384*20
    float* mbuf = ws + 16384000 + 327680;   // 16384*4

    dim3 blk(256);
    // encoder
    gemm_bias2<true ><<<dim3(8, 128), blk, 0, stream>>>(x,    enc_w0, enc_b0, buf1, 16384, 500, 39);
    gemm_bias2<true ><<<dim3(8, 128), blk, 0, stream>>>(buf1, enc_w1, enc_b1, buf2, 16384, 500, 500);
    gemm_bias2<false><<<dim3(1, 128), blk, 0, stream>>>(buf2, enc_w2, enc_b2, hbuf, 16384, 20, 500);
    // LTC scan
    ltc_scan<<<dim3(32), dim3(512), 0, stream>>>(hbuf, gleak, vleak, cm, w, mu, sigma, erev,
                                                 sw, smu, ssigma, serev, in_w, in_b, out_w, out_b, mbuf);
    // decoder
    dec_l1<<<dim3(8000), blk, 0, stream>>>(mbuf, dec_w0, dec_b0, buf1);
    gemm_bias2<true ><<<dim3(8, 128), blk, 0, stream>>>(buf1, dec_w1, dec_b1, buf2, 16384, 500, 500);
    gemm_bias2<false><<<dim3(1, 128), blk, 0, stream>>>(buf2, dec_w2, dec_b2, (float*)d_out, 16384, 30, 500);
}